// Round 8
// baseline (6661.420 us; speedup 1.0000x reference)
//
#include <hip/hip_runtime.h>
#include <stdint.h>

typedef __attribute__((ext_vector_type(8))) short short8;
typedef __attribute__((ext_vector_type(4))) float f32x4;
typedef __attribute__((ext_vector_type(2))) unsigned long long u64x2;

#define T_SZ 512

// ws layout (bytes)
#define XP_OFF    0ull                 // xp (bf16): 16384*4096*2 = 134217728
#define UPERM_OFF 134217728ull         // Uperm (bf16): 8 MB
#define WPERM_OFF 142606336ull         // Wperm (bf16): 4 MB
#define HBUF_OFF  146800640ull         // hbuf: 2*32*1024*2 = 131072
#define BAR_OFF   146931712ull         // flags: 2 teams x 1024 dwords (4KB apart)

static __device__ __forceinline__ float b2f(unsigned short u) {
  unsigned v = ((unsigned)u) << 16;
  return __builtin_bit_cast(float, v);
}
static __device__ __forceinline__ unsigned short f2b(float f) {
  unsigned u = __builtin_bit_cast(unsigned, f);
  u += 0x7fffu + ((u >> 16) & 1u);   // RNE
  return (unsigned short)(u >> 16);
}
static __device__ __forceinline__ float sigm(float x) {
  return 1.0f / (1.0f + __expf(-x));
}
static __device__ __forceinline__ float tanh_f(float x) {
  return 1.0f - 2.0f / (__expf(2.0f * x) + 1.0f);
}

// ---- one-time permutation of U (f32 -> bf16) into MFMA B-fragment layout ----
// frag F = ((cg*4 + kq)*4 + g)*8 + kk ; lane l holds B[k][n],
// k = kq*256+kk*32+(l>>4)*8+j, n = g*1024+cg*16+(l&15)
__global__ void permute_U(const float* __restrict__ U, unsigned short* __restrict__ Up) {
  int t = blockIdx.x * 256 + threadIdx.x;        // 524288 threads
  int l = t & 63;
  int F = t >> 6;                                 // 8192 frags
  int kk = F & 7, g = (F >> 3) & 3, kq = (F >> 5) & 3, cg = F >> 7;
  int k0 = kq * 256 + kk * 32 + (l >> 4) * 8;
  int n  = g * 1024 + cg * 16 + (l & 15);
  unsigned short v[8];
#pragma unroll
  for (int j = 0; j < 8; j++) v[j] = f2b(U[(size_t)(k0 + j) * 4096 + n]);
  unsigned short* dst = Up + (size_t)t * 8;
#pragma unroll
  for (int j = 0; j < 8; j++) dst[j] = v[j];
}

// frag F = nt*16 + kk ; k = kk*32+(l>>4)*8+j (k<512), n = nt*16+(l&15)
__global__ void permute_W(const float* __restrict__ W, unsigned short* __restrict__ Wp) {
  int t = blockIdx.x * 256 + threadIdx.x;        // 262144 threads
  int l = t & 63;
  int F = t >> 6;                                 // 4096 frags
  int kk = F & 15, nt = F >> 4;
  int k0 = kk * 32 + (l >> 4) * 8;
  int n  = nt * 16 + (l & 15);
  unsigned short v[8];
#pragma unroll
  for (int j = 0; j < 8; j++) v[j] = f2b(W[(size_t)(k0 + j) * 4096 + n]);
  unsigned short* dst = Wp + (size_t)t * 8;
#pragma unroll
  for (int j = 0; j < 8; j++) dst[j] = v[j];
}

__global__ void init_zero(unsigned short* __restrict__ hbuf, unsigned* __restrict__ bar) {
  int t = blockIdx.x * 256 + threadIdx.x;
  if (t < 16384) ((unsigned long long*)hbuf)[t] = 0ull;   // 2*32*1024 bf16
  if (t < 2048) bar[t] = 0u;
}

// ---- Phase B: xp[m][n] = X[m][:] @ W[:][n] + b[n], M=16384 N=4096 K=512 ----
__global__ __launch_bounds__(256) void xproj_gemm(
    const float* __restrict__ X,
    const unsigned short* __restrict__ Wp,
    const float* __restrict__ bias,
    unsigned short* __restrict__ xp) {
  const int tid = threadIdx.x;
  const int l = tid & 63;
  const int w = tid >> 6;
  const int wr = w >> 1, wc = w & 1;
  const int bn = blockIdx.x;   // 32
  const int bm = blockIdx.y;   // 128
  const int quad = l >> 4, lane16 = l & 15;
  __shared__ unsigned short lA[128 * 72];   // 128 rows x 64 k (bf16), +8 pad

  f32x4 acc[4][4];
#pragma unroll
  for (int i = 0; i < 4; i++)
#pragma unroll
    for (int j = 0; j < 4; j++) acc[i][j] = (f32x4){0.f, 0.f, 0.f, 0.f};

  const int m0 = bm * 128;
  const int sr = tid >> 3;          // 0..31
  const int sc = (tid & 7) * 8;     // 0..56 (floats)

  for (int ks = 0; ks < 8; ks++) {
    __syncthreads();
#pragma unroll
    for (int it = 0; it < 4; it++) {
      int row = sr + it * 32;
      const float* src = X + (size_t)(m0 + row) * 512 + ks * 64 + sc;
      float4 a = *(const float4*)(src);
      float4 c = *(const float4*)(src + 4);
      unsigned short tmp[8] = {f2b(a.x), f2b(a.y), f2b(a.z), f2b(a.w),
                               f2b(c.x), f2b(c.y), f2b(c.z), f2b(c.w)};
      *(int4*)(lA + row * 72 + sc) = *(const int4*)tmp;
    }
    __syncthreads();
#pragma unroll
    for (int kk = 0; kk < 2; kk++) {
      short8 af[4], bf[4];
#pragma unroll
      for (int i = 0; i < 4; i++)
        af[i] = *(const short8*)(lA + (wr * 64 + i * 16 + lane16) * 72 + kk * 32 + quad * 8);
#pragma unroll
      for (int j = 0; j < 4; j++) {
        int F = (bn * 8 + wc * 4 + j) * 16 + ks * 2 + kk;
        bf[j] = *(const short8*)(Wp + (size_t)(F * 64 + l) * 8);
      }
#pragma unroll
      for (int i = 0; i < 4; i++)
#pragma unroll
        for (int j = 0; j < 4; j++)
          acc[i][j] = __builtin_amdgcn_mfma_f32_16x16x32_bf16(af[i], bf[j], acc[i][j], 0, 0, 0);
    }
  }
#pragma unroll
  for (int j = 0; j < 4; j++) {
    int n = bn * 128 + wc * 64 + j * 16 + lane16;
    float bj = bias[n];
#pragma unroll
    for (int i = 0; i < 4; i++)
#pragma unroll
      for (int r = 0; r < 4; r++) {
        int m = m0 + wr * 64 + i * 16 + quad * 4 + r;
        xp[(size_t)m * 4096 + n] = f2b(acc[i][j][r] + bj);
      }
  }
}

// ---- Phase C: persistent recurrent kernel ----
// 128 blocks x 256 threads. block: mh = batch-half (16 rows), cg = 16 h-cols.
// h via sc0sc1 write-through stores + bypass loads.
// PER-WAVE RELEASE flags (R7 post-mortem): each wave's lane-0 posts its own
// flag with RELEASE — orders that wave's h-stores before its flag without
// relying on cross-wave drain semantics (the suspected R7 race). out is
// write-through too, so the release's buffer_wbl2 walks a clean L2 (~free).
// Consumer wave kq polls the 64 wave-flags of its quarter's 16 producers
// (one flag per lane + ballot).
__global__ __launch_bounds__(256, 1) void lstm_rec(
    const unsigned short* __restrict__ xp,
    const unsigned short* __restrict__ Up,
    unsigned short* __restrict__ hbuf,   // [2][32][1024] bf16
    unsigned* __restrict__ bar,
    float* __restrict__ out) {           // [32][512][1024] f32
  const int tid = threadIdx.x;
  const int l = tid & 63;
  const int kq = tid >> 6;           // wave id = K-quarter
  const int bid = blockIdx.x;        // 0..127
  const int mh = bid >> 6;           // team (batch half)
  const int cg = bid & 63;           // h-col group
  const int quad = l >> 4, lane16 = l & 15;

  __shared__ float zbuf[4][4][16][17];         // [kq][gate][b][col]

  // preload B fragments (U slice) into registers: 4 gates x 8 k-frags x 16B
  short8 bfr[4][8];
#pragma unroll
  for (int g = 0; g < 4; g++)
#pragma unroll
    for (int kk = 0; kk < 8; kk++) {
      int F = ((cg * 4 + kq) * 4 + g) * 8 + kk;
      bfr[g][kk] = *(const short8*)(Up + (size_t)(F * 64 + l) * 8);
    }

  float c_st = 0.0f;
  const int bl = tid >> 4;           // 0..15
  const int jj = tid & 15;
  const int bglob = mh * 16 + bl;

  // flags (dwords): team base mh*1024; quarter q at [q*64, q*64+64),
  // slot = (producer cg & 15)*4 + producer-wave.
  unsigned* team_flags = bar + mh * 1024;
  unsigned* my_flag    = team_flags + (cg >> 4) * 64 + (cg & 15) * 4 + kq;
  unsigned* poll_flag  = team_flags + kq * 64 + l;   // 64 lanes <-> 64 flags

  // A-frag source in u64 units: row = batch (mh*16+lane16), k-quarter kq
  const unsigned long long* hq = (const unsigned long long*)hbuf;
  const size_t rowbase = (size_t)(mh * 16 + lane16) * 256 + (size_t)kq * 64 + (size_t)quad * 2;

  // xp(0) preload (normal cached; produced by earlier dispatch)
  const unsigned short* xpbase =
      xp + (size_t)bglob * T_SZ * 4096 + (size_t)cg * 16 + jj;
  unsigned short xr0 = xpbase[0];
  unsigned short xr1 = xpbase[1024];
  unsigned short xr2 = xpbase[2048];
  unsigned short xr3 = xpbase[3072];

#pragma unroll 1
  for (int t = 0; t < T_SZ; t++) {
    // h(t) MFMA A-frags direct from global via relaxed agent atomics
    const unsigned long long* hb = hq + (size_t)(t & 1) * 8192 + rowbase;
    short8 af[8];
#pragma unroll
    for (int kk = 0; kk < 8; kk++) {
      u64x2 tmp;
      tmp.x = __hip_atomic_load(hb + kk * 8,     __ATOMIC_RELAXED, __HIP_MEMORY_SCOPE_AGENT);
      tmp.y = __hip_atomic_load(hb + kk * 8 + 1, __ATOMIC_RELAXED, __HIP_MEMORY_SCOPE_AGENT);
      af[kk] = __builtin_bit_cast(short8, tmp);
    }

    // z partial GEMM: wave kq covers k in [kq*256, kq*256+256)
    f32x4 acc[4];
#pragma unroll
    for (int g = 0; g < 4; g++) acc[g] = (f32x4){0.f, 0.f, 0.f, 0.f};
#pragma unroll
    for (int kk = 0; kk < 8; kk++) {
#pragma unroll
      for (int g = 0; g < 4; g++)
        acc[g] = __builtin_amdgcn_mfma_f32_16x16x32_bf16(af[kk], bfr[g][kk], acc[g], 0, 0, 0);
    }
#pragma unroll
    for (int g = 0; g < 4; g++)
#pragma unroll
      for (int r = 0; r < 4; r++)
        zbuf[kq][g][quad * 4 + r][lane16] = acc[g][r];
    __syncthreads();                 // (A) zbuf ready

    // elementwise: thread -> (batch bl, h-col jj)
    float z0 = zbuf[0][0][bl][jj] + zbuf[1][0][bl][jj] + zbuf[2][0][bl][jj] + zbuf[3][0][bl][jj] + b2f(xr0);
    float z1 = zbuf[0][1][bl][jj] + zbuf[1][1][bl][jj] + zbuf[2][1][bl][jj] + zbuf[3][1][bl][jj] + b2f(xr1);
    float z2 = zbuf[0][2][bl][jj] + zbuf[1][2][bl][jj] + zbuf[2][2][bl][jj] + zbuf[3][2][bl][jj] + b2f(xr2);
    float z3 = zbuf[0][3][bl][jj] + zbuf[1][3][bl][jj] + zbuf[2][3][bl][jj] + zbuf[3][3][bl][jj] + b2f(xr3);
    float ig = sigm(z0);
    float fg = sigm(z1);
    float gg = tanh_f(z2);
    float og = sigm(z3);
    c_st = fg * c_st + ig * gg;
    float h = og * tanh_f(c_st);

    // publish h(t+1)-buffer: pack bf16 pair, even lanes write-through dwords
    unsigned own = (unsigned)f2b(h);
    unsigned other = (unsigned)__shfl_xor((int)own, 1);
    if (!(jj & 1)) {
      unsigned packed = own | (other << 16);        // low = col jj, high = jj+1
      unsigned* dst = (unsigned*)(hbuf +
          ((size_t)((t + 1) & 1) * 32 + bglob) * 1024 + (size_t)cg * 16 + jj);
      __hip_atomic_store(dst, packed, __ATOMIC_RELAXED, __HIP_MEMORY_SCOPE_AGENT);
    }

    __syncthreads();                 // (B) all waves finished elementwise/zbuf reads
    // per-wave RELEASE flag: orders THIS wave's h-stores before the flag
    if ((tid & 63) == 0)
      __hip_atomic_store(my_flag, (unsigned)(t + 1),
                         __ATOMIC_RELEASE, __HIP_MEMORY_SCOPE_AGENT);

    // post-flag tail: write-through out store + xp(t+1) prefetch overlap poll
    __hip_atomic_store((unsigned*)(out + ((size_t)bglob * T_SZ + t) * 1024 + cg * 16 + jj),
                       __builtin_bit_cast(unsigned, h),
                       __ATOMIC_RELAXED, __HIP_MEMORY_SCOPE_AGENT);
    {
      int tn = (t + 1 < T_SZ) ? t + 1 : t;
      const unsigned short* xpn = xpbase + (size_t)tn * 4096;
      xr0 = xpn[0];
      xr1 = xpn[1024];
      xr2 = xpn[2048];
      xr3 = xpn[3072];
    }

    // wave kq waits for all 4 wave-flags of its quarter's 16 producer blocks
    {
      const unsigned target = (unsigned)(t + 1);
      while (true) {
        unsigned v = __hip_atomic_load(poll_flag, __ATOMIC_RELAXED,
                                       __HIP_MEMORY_SCOPE_AGENT);
        if (__ballot(v < target) == 0ull) break;
        __builtin_amdgcn_s_sleep(1);
      }
    }
  }
}

extern "C" void kernel_launch(void* const* d_in, const int* in_sizes, int n_in,
                              void* d_out, int out_size, void* d_ws, size_t ws_size,
                              hipStream_t stream) {
  const float* X    = (const float*)d_in[0];  // [32][512][512]  f32
  const float* W    = (const float*)d_in[1];  // [512][4096]     f32
  const float* U    = (const float*)d_in[2];  // [1024][4096]    f32
  const float* bias = (const float*)d_in[3];  // [4096]          f32
  float* out = (float*)d_out;                 // [32][512][1024] f32

  char* ws = (char*)d_ws;
  unsigned short* xp   = (unsigned short*)(ws + XP_OFF);
  unsigned short* Up   = (unsigned short*)(ws + UPERM_OFF);
  unsigned short* Wp   = (unsigned short*)(ws + WPERM_OFF);
  unsigned short* hbuf = (unsigned short*)(ws + HBUF_OFF);
  unsigned*       bar  = (unsigned*)(ws + BAR_OFF);

  hipLaunchKernelGGL(permute_U, dim3(2048), dim3(256), 0, stream, U, Up);
  hipLaunchKernelGGL(permute_W, dim3(1024), dim3(256), 0, stream, W, Wp);
  hipLaunchKernelGGL(init_zero, dim3(64), dim3(256), 0, stream, hbuf, bar);
  hipLaunchKernelGGL(xproj_gemm, dim3(32, 128), dim3(256), 0, stream, X, Wp, bias, xp);
  hipLaunchKernelGGL(lstm_rec, dim3(128), dim3(256), 0, stream, xp, Up, hbuf, bar, out);
}

// Round 9
// 3061.125 us; speedup vs baseline: 2.1761x; 2.1761x over previous
//
#include <hip/hip_runtime.h>
#include <stdint.h>

typedef __attribute__((ext_vector_type(8))) short short8;
typedef __attribute__((ext_vector_type(4))) float f32x4;
typedef __attribute__((ext_vector_type(4))) unsigned u32x4;

#define T_SZ 512

// ws layout (bytes)
#define XP_OFF    0ull                 // xp (bf16): 16384*4096*2 = 134217728
#define UPERM_OFF 134217728ull         // Uperm (bf16): 8 MB
#define WPERM_OFF 142606336ull         // Wperm (bf16): 4 MB
#define HBUF_OFF  146800640ull         // hbuf: 4 slabs x 32 x 1024 dwords = 512 KB

static __device__ __forceinline__ float b2f(unsigned short u) {
  unsigned v = ((unsigned)u) << 16;
  return __builtin_bit_cast(float, v);
}
static __device__ __forceinline__ unsigned short f2b(float f) {
  unsigned u = __builtin_bit_cast(unsigned, f);
  u += 0x7fffu + ((u >> 16) & 1u);   // RNE
  return (unsigned short)(u >> 16);
}
static __device__ __forceinline__ float sigm(float x) {
  return 1.0f / (1.0f + __expf(-x));
}
static __device__ __forceinline__ float tanh_f(float x) {
  return 1.0f - 2.0f / (__expf(2.0f * x) + 1.0f);
}

// ---- one-time permutation of U (f32 -> bf16) into MFMA B-fragment layout ----
__global__ void permute_U(const float* __restrict__ U, unsigned short* __restrict__ Up) {
  int t = blockIdx.x * 256 + threadIdx.x;        // 524288 threads
  int l = t & 63;
  int F = t >> 6;                                 // 8192 frags
  int kk = F & 7, g = (F >> 3) & 3, kq = (F >> 5) & 3, cg = F >> 7;
  int k0 = kq * 256 + kk * 32 + (l >> 4) * 8;
  int n  = g * 1024 + cg * 16 + (l & 15);
  unsigned short v[8];
#pragma unroll
  for (int j = 0; j < 8; j++) v[j] = f2b(U[(size_t)(k0 + j) * 4096 + n]);
  unsigned short* dst = Up + (size_t)t * 8;
#pragma unroll
  for (int j = 0; j < 8; j++) dst[j] = v[j];
}

__global__ void permute_W(const float* __restrict__ W, unsigned short* __restrict__ Wp) {
  int t = blockIdx.x * 256 + threadIdx.x;        // 262144 threads
  int l = t & 63;
  int F = t >> 6;                                 // 4096 frags
  int kk = F & 15, nt = F >> 4;
  int k0 = kk * 32 + (l >> 4) * 8;
  int n  = nt * 16 + (l & 15);
  unsigned short v[8];
#pragma unroll
  for (int j = 0; j < 8; j++) v[j] = f2b(W[(size_t)(k0 + j) * 4096 + n]);
  unsigned short* dst = Wp + (size_t)t * 8;
#pragma unroll
  for (int j = 0; j < 8; j++) dst[j] = v[j];
}

// hbuf: 4 slabs x 32768 dwords. slab 0 = (h=0, tag=0); slabs 1..3 = tag 0xFFFF.
__global__ void init_hbuf(unsigned* __restrict__ hbuf) {
  int t = blockIdx.x * 256 + threadIdx.x;        // 131072 threads
  hbuf[t] = (t < 32768) ? 0u : 0xFFFFu;
}

// ---- Phase B: xp[m][n] = X[m][:] @ W[:][n] + b[n], M=16384 N=4096 K=512 ----
__global__ __launch_bounds__(256) void xproj_gemm(
    const float* __restrict__ X,
    const unsigned short* __restrict__ Wp,
    const float* __restrict__ bias,
    unsigned short* __restrict__ xp) {
  const int tid = threadIdx.x;
  const int l = tid & 63;
  const int w = tid >> 6;
  const int wr = w >> 1, wc = w & 1;
  const int bn = blockIdx.x;   // 32
  const int bm = blockIdx.y;   // 128
  const int quad = l >> 4, lane16 = l & 15;
  __shared__ unsigned short lA[128 * 72];

  f32x4 acc[4][4];
#pragma unroll
  for (int i = 0; i < 4; i++)
#pragma unroll
    for (int j = 0; j < 4; j++) acc[i][j] = (f32x4){0.f, 0.f, 0.f, 0.f};

  const int m0 = bm * 128;
  const int sr = tid >> 3;
  const int sc = (tid & 7) * 8;

  for (int ks = 0; ks < 8; ks++) {
    __syncthreads();
#pragma unroll
    for (int it = 0; it < 4; it++) {
      int row = sr + it * 32;
      const float* src = X + (size_t)(m0 + row) * 512 + ks * 64 + sc;
      float4 a = *(const float4*)(src);
      float4 c = *(const float4*)(src + 4);
      unsigned short tmp[8] = {f2b(a.x), f2b(a.y), f2b(a.z), f2b(a.w),
                               f2b(c.x), f2b(c.y), f2b(c.z), f2b(c.w)};
      *(int4*)(lA + row * 72 + sc) = *(const int4*)tmp;
    }
    __syncthreads();
#pragma unroll
    for (int kk = 0; kk < 2; kk++) {
      short8 af[4], bf[4];
#pragma unroll
      for (int i = 0; i < 4; i++)
        af[i] = *(const short8*)(lA + (wr * 64 + i * 16 + lane16) * 72 + kk * 32 + quad * 8);
#pragma unroll
      for (int j = 0; j < 4; j++) {
        int F = (bn * 8 + wc * 4 + j) * 16 + ks * 2 + kk;
        bf[j] = *(const short8*)(Wp + (size_t)(F * 64 + l) * 8);
      }
#pragma unroll
      for (int i = 0; i < 4; i++)
#pragma unroll
        for (int j = 0; j < 4; j++)
          acc[i][j] = __builtin_amdgcn_mfma_f32_16x16x32_bf16(af[i], bf[j], acc[i][j], 0, 0, 0);
    }
  }
#pragma unroll
  for (int j = 0; j < 4; j++) {
    int n = bn * 128 + wc * 64 + j * 16 + lane16;
    float bj = bias[n];
#pragma unroll
    for (int i = 0; i < 4; i++)
#pragma unroll
      for (int r = 0; r < 4; r++) {
        int m = m0 + wr * 64 + i * 16 + quad * 4 + r;
        xp[(size_t)m * 4096 + n] = f2b(acc[i][j][r] + bj);
      }
  }
}

// ---- Phase C: persistent recurrent kernel — self-validating h transport ----
// NO flags, NO fences, NO release. h element = dword (h_bf16<<16 | step_tag),
// stored write-through (relaxed agent atomic, sc0sc1), consumed by spin-
// reloading until every dword carries the expected tag. Correctness needs
// only per-dword atomicity. 4 rotating slabs: entering step u proves all
// blocks >= u-2, so slab reuse at distance 4 cannot lap a reader; stale
// tags are detected and retried anyway. zbuf double-buffered in LDS ->
// ONE __syncthreads per step.
__global__ __launch_bounds__(256, 1) void lstm_rec(
    const unsigned short* __restrict__ xp,
    const unsigned short* __restrict__ Up,
    unsigned* __restrict__ hbuf,         // [4][32][1024] dwords
    float* __restrict__ out) {           // [32][512][1024] f32
  const int tid = threadIdx.x;
  const int l = tid & 63;
  const int kq = tid >> 6;           // wave = K-quarter
  const int bid = blockIdx.x;        // 0..127
  const int mh = bid >> 6;           // team (batch half)
  const int cg = bid & 63;           // h-col group
  const int quad = l >> 4, lane16 = l & 15;

  __shared__ float zbuf[2][4][4][16][17];      // [p][kq][gate][b][col]

  // preload B fragments (U slice) into registers: 4 gates x 8 k-frags x 16B
  short8 bfr[4][8];
#pragma unroll
  for (int g = 0; g < 4; g++)
#pragma unroll
    for (int kk = 0; kk < 8; kk++) {
      int F = ((cg * 4 + kq) * 4 + g) * 8 + kk;
      bfr[g][kk] = *(const short8*)(Up + (size_t)(F * 64 + l) * 8);
    }

  float c_st = 0.0f;
  const int bl = tid >> 4;           // 0..15
  const int jj = tid & 15;
  const int bglob = mh * 16 + bl;

  // consumer base: row = batch (mh*16+lane16), k-quarter kq (dword units)
  const unsigned rowoff = (unsigned)(mh * 16 + lane16) * 1024 + (unsigned)kq * 256;
  // producer store slot (dword units, within slab)
  const unsigned stoff = (unsigned)bglob * 1024 + (unsigned)cg * 16 + jj;

  // xp(0) preload (normal cached; produced by earlier dispatch)
  const unsigned short* xpbase =
      xp + (size_t)bglob * T_SZ * 4096 + (size_t)cg * 16 + jj;
  unsigned short xr0 = xpbase[0];
  unsigned short xr1 = xpbase[1024];
  unsigned short xr2 = xpbase[2048];
  unsigned short xr3 = xpbase[3072];

#pragma unroll 1
  for (int t = 0; t < T_SZ; t++) {
    // ---- consume h(t): spin until all 64 dwords/lane carry tag t ----
    const unsigned tag = (unsigned)t;
    const unsigned* hb32 = hbuf + (size_t)(t & 3) * 32768 + rowoff;
    short8 af[8];
    unsigned pend = 0xFFu;                       // wave-uniform frag bitmask
    while (pend) {
#pragma unroll
      for (int f = 0; f < 8; f++) {
        if (pend & (1u << f)) {
          const unsigned long long* p =
              (const unsigned long long*)(hb32 + f * 32 + quad * 8);
          unsigned bad = 0u;
          unsigned pk[4];
#pragma unroll
          for (int q = 0; q < 4; q++) {
            unsigned long long u = __hip_atomic_load(p + q, __ATOMIC_RELAXED,
                                                     __HIP_MEMORY_SCOPE_AGENT);
            unsigned lo = (unsigned)u, hi = (unsigned)(u >> 32);
            bad |= ((lo ^ tag) | (hi ^ tag)) & 0xFFFFu;
            pk[q] = (lo >> 16) | (hi & 0xFFFF0000u);
          }
          if (__ballot(bad != 0u) == 0ull) {
            pend &= ~(1u << f);
            u32x4 v = {pk[0], pk[1], pk[2], pk[3]};
            af[f] = __builtin_bit_cast(short8, v);
          }
        }
      }
      if (pend) __builtin_amdgcn_s_sleep(1);
    }

    // ---- z partial GEMM: wave kq covers k in [kq*256, kq*256+256) ----
    f32x4 acc[4];
#pragma unroll
    for (int g = 0; g < 4; g++) acc[g] = (f32x4){0.f, 0.f, 0.f, 0.f};
#pragma unroll
    for (int kk = 0; kk < 8; kk++) {
#pragma unroll
      for (int g = 0; g < 4; g++)
        acc[g] = __builtin_amdgcn_mfma_f32_16x16x32_bf16(af[kk], bfr[g][kk], acc[g], 0, 0, 0);
    }
    const int p = t & 1;
#pragma unroll
    for (int g = 0; g < 4; g++)
#pragma unroll
      for (int r = 0; r < 4; r++)
        zbuf[p][kq][g][quad * 4 + r][lane16] = acc[g][r];
    __syncthreads();                 // the ONLY barrier per step

    // ---- elementwise: thread -> (batch bl, h-col jj) ----
    float z0 = zbuf[p][0][0][bl][jj] + zbuf[p][1][0][bl][jj] + zbuf[p][2][0][bl][jj] + zbuf[p][3][0][bl][jj] + b2f(xr0);
    float z1 = zbuf[p][0][1][bl][jj] + zbuf[p][1][1][bl][jj] + zbuf[p][2][1][bl][jj] + zbuf[p][3][1][bl][jj] + b2f(xr1);
    float z2 = zbuf[p][0][2][bl][jj] + zbuf[p][1][2][bl][jj] + zbuf[p][2][2][bl][jj] + zbuf[p][3][2][bl][jj] + b2f(xr2);
    float z3 = zbuf[p][0][3][bl][jj] + zbuf[p][1][3][bl][jj] + zbuf[p][2][3][bl][jj] + zbuf[p][3][3][bl][jj] + b2f(xr3);
    float ig = sigm(z0);
    float fg = sigm(z1);
    float gg = tanh_f(z2);
    float og = sigm(z3);
    c_st = fg * c_st + ig * gg;
    float h = og * tanh_f(c_st);

    // ---- publish h(t+1): tagged dword, write-through, no ordering needed ----
    unsigned tagged = ((unsigned)f2b(h) << 16) | (unsigned)(t + 1);
    __hip_atomic_store(hbuf + (size_t)((t + 1) & 3) * 32768 + stoff, tagged,
                       __ATOMIC_RELAXED, __HIP_MEMORY_SCOPE_AGENT);

    // tail (overlaps other blocks' progress): out store + xp(t+1) prefetch
    out[((size_t)bglob * T_SZ + t) * 1024 + cg * 16 + jj] = h;
    {
      int tn = (t + 1 < T_SZ) ? t + 1 : t;
      const unsigned short* xpn = xpbase + (size_t)tn * 4096;
      xr0 = xpn[0];
      xr1 = xpn[1024];
      xr2 = xpn[2048];
      xr3 = xpn[3072];
    }
  }
}

extern "C" void kernel_launch(void* const* d_in, const int* in_sizes, int n_in,
                              void* d_out, int out_size, void* d_ws, size_t ws_size,
                              hipStream_t stream) {
  const float* X    = (const float*)d_in[0];  // [32][512][512]  f32
  const float* W    = (const float*)d_in[1];  // [512][4096]     f32
  const float* U    = (const float*)d_in[2];  // [1024][4096]    f32
  const float* bias = (const float*)d_in[3];  // [4096]          f32
  float* out = (float*)d_out;                 // [32][512][1024] f32

  char* ws = (char*)d_ws;
  unsigned short* xp   = (unsigned short*)(ws + XP_OFF);
  unsigned short* Up   = (unsigned short*)(ws + UPERM_OFF);
  unsigned short* Wp   = (unsigned short*)(ws + WPERM_OFF);
  unsigned*       hbuf = (unsigned*)(ws + HBUF_OFF);

  hipLaunchKernelGGL(permute_U, dim3(2048), dim3(256), 0, stream, U, Up);
  hipLaunchKernelGGL(permute_W, dim3(1024), dim3(256), 0, stream, W, Wp);
  hipLaunchKernelGGL(init_hbuf, dim3(512), dim3(256), 0, stream, hbuf);
  hipLaunchKernelGGL(xproj_gemm, dim3(32, 128), dim3(256), 0, stream, X, Wp, bias, xp);
  hipLaunchKernelGGL(lstm_rec, dim3(128), dim3(256), 0, stream, xp, Up, hbuf, out);
}